// Round 13
// baseline (371.584 us; speedup 1.0000x reference)
//
#include <hip/hip_runtime.h>
#include <hip/hip_cooperative_groups.h>
#include <stdint.h>

namespace cg = cooperative_groups;

typedef _Float16 h8v __attribute__((ext_vector_type(8)));
typedef _Float16 h4v __attribute__((ext_vector_type(4)));
typedef float f4v __attribute__((ext_vector_type(4)));
typedef _Float16 f16;

#define NB 8
#define CC 128
#define CB 64
#define NN 4096
#define L2E 1.4426950408889634f

#define GLD(gp, lp) __builtin_amdgcn_global_load_lds( \
    (const __attribute__((address_space(1))) void*)(gp), \
    (__attribute__((address_space(3))) void*)(lp), 16, 0, 0)

#define WAITV1() asm volatile("s_waitcnt vmcnt(1)" ::: "memory")
#define WAITV0() asm volatile("s_waitcnt vmcnt(0)" ::: "memory")
#define WAITL0() asm volatile("s_waitcnt lgkmcnt(0)" ::: "memory")

// ---------------------------------------------------------------------------
// Phase 0: pack weights into f16 MFMA-fragment order (distributed).
// wth pre-scaled by log2(e) for attn's exp2 softmax.
// ---------------------------------------------------------------------------
__device__ __forceinline__ void pack_body(int tg,
    const float* __restrict__ wth, const float* __restrict__ wph,
    const float* __restrict__ wg,  const float* __restrict__ wl,
    f16* __restrict__ wthp, f16* __restrict__ wphp,
    f16* __restrict__ wgp,  f16* __restrict__ wlp)
{
    if (tg < 8192){
        const int i = tg;
        {
            const int j = i & 7, lane = (i >> 3) & 63, kc = (i >> 9) & 3, ks = i >> 11;
            const int row = ks * 16 + (lane & 15);
            const int col = kc * 32 + ((lane >> 4) & 3) * 8 + j;
            wthp[i] = (f16)(wth[row * CC + col] * L2E);
            wphp[i] = (f16)(wph[row * CC + col]);
            wgp [i] = (f16)(wg [row * CC + col]);
        }
        {
            const int j = i & 7, lane = (i >> 3) & 63, kc = (i >> 9) & 1, cs = i >> 10;
            const int row = cs * 16 + (lane & 15);
            const int col = kc * 32 + ((lane >> 4) & 3) * 8 + j;
            wlp[i] = (f16)(wl[row * CB + col]);
        }
    }
}

// ---------------------------------------------------------------------------
// Phase 1: projections (R24 body, proven). SM layout: xT[64][136] | rep[8][1152]
// ---------------------------------------------------------------------------
__device__ __forceinline__ void proj_body(char* SM, int bid, int t,
    const float* __restrict__ x, const f16* __restrict__ wthp,
    const f16* __restrict__ wphp, const f16* __restrict__ wgp,
    f16* __restrict__ thetaT, f16* __restrict__ phiT, f16* __restrict__ gbuf)
{
    f16 (*xT)[136] = (f16(*)[136])SM;
    f16* rep = (f16*)(SM + 17408);              // [8][16*72]
    const int b  = bid & 7;
    const int n0 = (bid >> 3) << 6;

    #pragma unroll
    for (int i = 0; i < 4; i++){
        int v  = t + 512 * i;
        int c  = v >> 4;
        int j0 = (v & 15) << 2;
        const f4v xv = *(const f4v*)&x[((size_t)(b * CC + c)) * NN + n0 + j0];
        #pragma unroll
        for (int jj = 0; jj < 4; jj++) xT[j0 + jj][c] = (f16)xv[jj];
    }
    __syncthreads();

    const int w = t >> 6, lane = t & 63, quad = lane >> 4, l15 = lane & 15;
    const int wq = w & 3, grp = w >> 2;
    const int rrow = lane >> 3, rcol = (lane & 7) * 8;

    h8v bx[4];
    #pragma unroll
    for (int kc = 0; kc < 4; kc++)
        bx[kc] = *(const h8v*)&xT[wq * 16 + l15][kc * 32 + quad * 8];

    // ---- theta (grp==0) / phi (grp==1) for n-group wq ----
    {
        const f16* WP = (grp == 0) ? wthp : wphp;
        f16* OUT      = (grp == 0) ? thetaT : phiT;
        for (int ks = 0; ks < 4; ks++){
            f4v acc = {0.f, 0.f, 0.f, 0.f};
            #pragma unroll
            for (int kc = 0; kc < 4; kc++){
                const h8v af = *(const h8v*)&WP[(ks * 4 + kc) * 512 + lane * 8];
                acc = __builtin_amdgcn_mfma_f32_16x16x32_f16(af, bx[kc], acc, 0, 0, 0);
            }
            h4v pv;
            #pragma unroll
            for (int r = 0; r < 4; r++) pv[r] = (f16)acc[r];
            *(h4v*)&rep[w * 1152 + l15 * 72 + ks * 16 + quad * 4] = pv;
        }
        #pragma unroll
        for (int j = 0; j < 2; j++){
            const h8v vv = *(const h8v*)&rep[w * 1152 + (rrow + 8 * j) * 72 + rcol];
            *(h8v*)&OUT[((size_t)(b * NN + n0 + wq * 16 + rrow + 8 * j)) * CB + rcol] = vv;
        }
    }
    __syncthreads();   // g below reuses rep[0..3]; theta reads must complete

    // ---- g: wave w -> cb-group wq, ns-half grp (rep cols disjoint) ----
    h8v bw[4];
    #pragma unroll
    for (int kc = 0; kc < 4; kc++)
        bw[kc] = *(const h8v*)&wgp[(wq * 4 + kc) * 512 + lane * 8];
    #pragma unroll
    for (int ns2 = 0; ns2 < 2; ns2++){
        const int ns = grp * 2 + ns2;
        f4v acc = {0.f, 0.f, 0.f, 0.f};
        #pragma unroll
        for (int kc = 0; kc < 4; kc++){
            const h8v af = *(const h8v*)&xT[ns * 16 + l15][kc * 32 + quad * 8];
            acc = __builtin_amdgcn_mfma_f32_16x16x32_f16(af, bw[kc], acc, 0, 0, 0);
        }
        h4v pv;
        #pragma unroll
        for (int r = 0; r < 4; r++) pv[r] = (f16)acc[r];
        *(h4v*)&rep[wq * 1152 + l15 * 72 + ns * 16 + quad * 4] = pv;
    }
    __syncthreads();   // both halves of rep[wq] complete
    {
        const int row = rrow + 8 * grp;
        const h8v vv = *(const h8v*)&rep[wq * 1152 + row * 72 + rcol];
        *(h8v*)&gbuf[((size_t)(b * CB + wq * 16 + row)) * NN + n0 + rcol] = vv;
    }
}

// ---------------------------------------------------------------------------
// Phase 2: fused attention + final projection + residual (R23 body, proven).
// P-in-register sigma PV, pre-permuted GG via reg-staged g, 3-deep gl_lds ph,
// counted vmcnt(1), raw barriers, STEPK compile-time slots, shuffle-free
// defer-max.
// ---------------------------------------------------------------------------
__device__ __forceinline__ void attn_body(char* SM, int bid, int t,
    const f16* __restrict__ thetaT, const f16* __restrict__ phiT,
    const f16* __restrict__ gbuf, const f16* __restrict__ wlp,
    const float* __restrict__ x, float* __restrict__ out)
{
    f16*   const PH  = (f16*)SM;                // [3][4096]   24576 B
    f16*   const GG  = (f16*)(SM + 24576);      // [3][4096]   24576 B
    // epilogue overlays (staging dead):
    float* const MG  = (float*)SM;              // [4][16][68] 17408 B
    float* const ML  = (float*)(SM + 17408);    // [4][16][2]    512 B
    float* const FO  = (float*)SM;              // [128][68]   34816 B
    f16*   const YY  = (f16*)(SM + 36864);      // [64][72]     9216 B

    const int b  = bid & 7;                     // batch -> XCD swizzle
    const int q0 = (bid >> 3) << 6;
    const int w  = t >> 6;                      // 0..7
    const int lane = t & 63, quad = lane >> 4, l15 = lane & 15;
    const int wq = w & 3;                       // query group
    const int h  = w >> 2;                      // key half of 64-key pair
    const int n0 = q0 + wq * 16;

    // theta fragments (16 queries per wave)
    const size_t trow = ((size_t)(b * NN + n0 + l15)) * CB;
    const h8v a0 = *(const h8v*)&thetaT[trow + quad * 8];
    const h8v a1 = *(const h8v*)&thetaT[trow + 32 + quad * 8];

    // ---- staging (all 512 threads; srow = key/cb row 0..63 of the pair) ----
    const int srow = t >> 3;
    const int skg  = t & 7;
    const f16* pS = phiT + ((size_t)(b * NN + srow)) * CB + (skg ^ (srow & 7)) * 8;
    const f16* pG = gbuf + ((size_t)(b * CB + srow)) * NN + skg * 8;
    // g sigma-store: this thread's 8 keys = skg*8..+7 -> 2 chunks x 4 f16
    const int sgs = (srow >> 1) & 3;
    const int cA  = (2 * (skg & 3)) & 3;
    const int gdA = (skg >> 2) * 2048 + srow * 32 + ((cA      ^ sgs) * 8) + ((skg >> 1) & 1) * 4;
    const int gdB = (skg >> 2) * 2048 + srow * 32 + (((cA | 1) ^ sgs) * 8) + ((skg >> 1) & 1) * 4;

    // read swizzles
    const int so0 = (quad ^ (l15 & 7)) * 8;           // ph b128 chunk
    const int so1 = so0 ^ 32;
    const int gvs = (quad ^ ((l15 >> 1) & 3)) * 8;    // GG sigma b128 chunk

    // precomputed base pointers; all slot/tt selects become imm offsets
    const f16* const PB0 = PH + h * 2048 + l15 * 64 + so0;
    const f16* const PB1 = PH + h * 2048 + l15 * 64 + so1;
    const f16* const GB  = GG + h * 2048 + l15 * 32 + gvs;
    f16* const WA = GG + gdA;
    f16* const WB = GG + gdB;
    f16* const PD = PH + t * 8;

    // ---- prologue: g pairs 0,1 -> regs; ph pairs 0,1 -> slots 0,1 ----
    h8v gA = *(const h8v*)pG;                   // g pair 0
    h8v gB = *(const h8v*)(pG + 64);            // g pair 1
    GLD(pS,                    PD);
    GLD(pS + (size_t)64 * CB,  PD + 4096);
    pG += 128;                                  // -> pair 2
    pS += (size_t)128 * CB;                     // -> pair 2
    {   // write g pair 0 -> slot 0
        h4v lo_, hi_;
        #pragma unroll
        for (int j = 0; j < 4; j++){ lo_[j] = gA[j]; hi_[j] = gA[4 + j]; }
        *(h4v*)&WA[0] = lo_;
        *(h4v*)&WB[0] = hi_;
    }

    float mrun = -1e30f, lrun = 0.f;
    const f4v zf = {0.f, 0.f, 0.f, 0.f};
    f4v o[4];
    #pragma unroll
    for (int tt = 0; tt < 4; tt++) o[tt] = zf;

// STEPK(RC, V1, DO_W, DO_L, gw, gl): compute pair with slot RC (literal);
// write g-next from gw into slot (RC+1)%3; load g(m+2)->gl; GLD ph(m+2)
// into slot (RC+2)%3.
#define STEPK(RC, V1, DO_W, DO_L, gw, gl) do {                              \
    if (V1) WAITV1(); else WAITV0();                                        \
    WAITL0();                                                               \
    __builtin_amdgcn_s_barrier();                                           \
    asm volatile("" ::: "memory");                                          \
    if (DO_W){                                                              \
        h4v lo_, hi_;                                                       \
        _Pragma("unroll")                                                   \
        for (int j = 0; j < 4; j++){ lo_[j] = gw[j]; hi_[j] = gw[4 + j]; }  \
        *(h4v*)&WA[((RC + 1) % 3) * 4096] = lo_;                            \
        *(h4v*)&WB[((RC + 1) % 3) * 4096] = hi_;                            \
    }                                                                       \
    if (DO_L){                                                              \
        gl = *(const h8v*)pG;  pG += 64;                                    \
        __builtin_amdgcn_sched_barrier(0);                                  \
        GLD(pS, PD + ((RC + 2) % 3) * 4096);                                \
        pS += (size_t)64 * CB;                                              \
    }                                                                       \
    f4v s0_, s1_;                                                           \
    __builtin_amdgcn_s_setprio(1);                                          \
    {                                                                       \
        const h8v pb0 = *(const h8v*)(PB0 + RC * 4096);                     \
        const h8v pb1 = *(const h8v*)(PB1 + RC * 4096);                     \
        f4v sv = zf;                                                        \
        sv = __builtin_amdgcn_mfma_f32_16x16x32_f16(pb0, a0, sv, 0, 0, 0);  \
        sv = __builtin_amdgcn_mfma_f32_16x16x32_f16(pb1, a1, sv, 0, 0, 0);  \
        s0_ = sv;                                                           \
        const h8v pb2 = *(const h8v*)(PB0 + RC * 4096 + 1024);              \
        const h8v pb3 = *(const h8v*)(PB1 + RC * 4096 + 1024);              \
        f4v sw = zf;                                                        \
        sw = __builtin_amdgcn_mfma_f32_16x16x32_f16(pb2, a0, sw, 0, 0, 0);  \
        sw = __builtin_amdgcn_mfma_f32_16x16x32_f16(pb3, a1, sw, 0, 0, 0);  \
        s1_ = sw;                                                           \
    }                                                                       \
    __builtin_amdgcn_s_setprio(0);                                          \
    float smax_ = fmaxf(fmaxf(s0_[0], s0_[1]), fmaxf(s0_[2], s0_[3]));      \
    smax_ = fmaxf(smax_, fmaxf(fmaxf(s1_[0], s1_[1]), fmaxf(s1_[2], s1_[3])));\
    if (__any(smax_ - mrun > 8.f)){                                         \
        smax_ = fmaxf(smax_, __shfl_xor(smax_, 16));                        \
        smax_ = fmaxf(smax_, __shfl_xor(smax_, 32));                        \
        const float mn_ = fmaxf(mrun, smax_);                               \
        const float al_ = __builtin_amdgcn_exp2f(mrun - mn_);               \
        mrun = mn_;                                                         \
        lrun *= al_;                                                        \
        _Pragma("unroll")                                                   \
        for (int tt = 0; tt < 4; tt++)                                      \
            _Pragma("unroll")                                               \
            for (int r = 0; r < 4; r++)                                     \
                o[tt][r] *= al_;                                            \
    }                                                                       \
    float lsum_ = 0.f;                                                      \
    h8v pa_;                                                                \
    _Pragma("unroll")                                                       \
    for (int r = 0; r < 4; r++){                                            \
        float p_ = __builtin_amdgcn_exp2f(s0_[r] - mrun);                   \
        lsum_ += p_;  pa_[r] = (f16)p_;                                     \
        float q_ = __builtin_amdgcn_exp2f(s1_[r] - mrun);                   \
        lsum_ += q_;  pa_[4 + r] = (f16)q_;                                 \
    }                                                                       \
    lrun += lsum_;                                                          \
    __builtin_amdgcn_s_setprio(1);                                          \
    o[0] = __builtin_amdgcn_mfma_f32_16x16x32_f16(                          \
        *(const h8v*)(GB + RC * 4096 +    0), pa_, o[0], 0, 0, 0);          \
    o[1] = __builtin_amdgcn_mfma_f32_16x16x32_f16(                          \
        *(const h8v*)(GB + RC * 4096 +  512), pa_, o[1], 0, 0, 0);          \
    o[2] = __builtin_amdgcn_mfma_f32_16x16x32_f16(                          \
        *(const h8v*)(GB + RC * 4096 + 1024), pa_, o[2], 0, 0, 0);          \
    o[3] = __builtin_amdgcn_mfma_f32_16x16x32_f16(                          \
        *(const h8v*)(GB + RC * 4096 + 1536), pa_, o[3], 0, 0, 0);          \
    __builtin_amdgcn_s_setprio(0);                                          \
} while (0)

    // m = 0..59 (all full steps): 10 x 6-unrolled
    for (int mm = 0; mm < 60; mm += 6){
        STEPK(0, 1, 1, 1, gB, gA);
        STEPK(1, 1, 1, 1, gA, gB);
        STEPK(2, 1, 1, 1, gB, gA);
        STEPK(0, 1, 1, 1, gA, gB);
        STEPK(1, 1, 1, 1, gB, gA);
        STEPK(2, 1, 1, 1, gA, gB);
    }
    STEPK(0, 1, 1, 1, gB, gA);   // m=60: stage pair 62 -> gA
    STEPK(1, 1, 1, 1, gA, gB);   // m=61: stage pair 63 -> gB
    STEPK(2, 1, 1, 0, gB, gA);   // m=62: write g(63)=gB, no loads
    STEPK(0, 0, 0, 0, gA, gB);   // m=63: drain, compute only
#undef STEPK

    // per-wave l reduce across quads (full l for this wave's key half)
    lrun += __shfl_xor(lrun, 16);
    lrun += __shfl_xor(lrun, 32);

    __syncthreads();   // K-loop done; staging region dead -> merge overlay

    if (h == 1){       // odd-half waves publish (m, l, O)
        #pragma unroll
        for (int tt2 = 0; tt2 < 4; tt2++)
            *(f4v*)&MG[wq * 1088 + l15 * 68 + tt2 * 16 + quad * 4] = o[tt2];
        if (lane < 16){
            ML[wq * 32 + lane * 2 + 0] = mrun;
            ML[wq * 32 + lane * 2 + 1] = lrun;
        }
    }
    __syncthreads();

    if (h == 0){       // even-half waves merge + normalize -> y (f16)
        const float m4 = ML[wq * 32 + l15 * 2 + 0];
        const float l4 = ML[wq * 32 + l15 * 2 + 1];
        const float M  = fmaxf(mrun, m4);
        const float e0 = __builtin_amdgcn_exp2f(mrun - M);
        const float e1 = __builtin_amdgcn_exp2f(m4 - M);
        const float inv = 1.0f / (lrun * e0 + l4 * e1);
        #pragma unroll
        for (int tt2 = 0; tt2 < 4; tt2++){
            const f4v o4 = *(const f4v*)&MG[wq * 1088 + l15 * 68 + tt2 * 16 + quad * 4];
            h4v yv;
            #pragma unroll
            for (int r = 0; r < 4; r++)
                yv[r] = (f16)((o[tt2][r] * e0 + o4[r] * e1) * inv);
            *(h4v*)&YY[(wq * 16 + l15) * 72 + tt2 * 16 + quad * 4] = yv;
        }
    }
    __syncthreads();

    // ---- out-GEMM: D[c][q] = wl(A) * y(B); 8 waves, 4 cs each ----
    const f4v zf2 = {0.f, 0.f, 0.f, 0.f};
    const h8v yB0 = *(const h8v*)&YY[(wq * 16 + l15) * 72 + quad * 8];
    const h8v yB1 = *(const h8v*)&YY[(wq * 16 + l15) * 72 + 32 + quad * 8];
    #pragma unroll
    for (int ci = 0; ci < 4; ci++){
        const int cs = h * 4 + ci;
        const h8v wa0 = *(const h8v*)&wlp[(cs * 2 + 0) * 512 + lane * 8];
        const h8v wa1 = *(const h8v*)&wlp[(cs * 2 + 1) * 512 + lane * 8];
        f4v acc = zf2;
        acc = __builtin_amdgcn_mfma_f32_16x16x32_f16(wa0, yB0, acc, 0, 0, 0);
        acc = __builtin_amdgcn_mfma_f32_16x16x32_f16(wa1, yB1, acc, 0, 0, 0);
        #pragma unroll
        for (int r = 0; r < 4; r++)
            FO[(cs * 16 + quad * 4 + r) * 68 + wq * 16 + l15] = acc[r];
    }
    __syncthreads();

    // ---- residual RMW: fully coalesced float4, 512 threads ----
    #pragma unroll
    for (int i = 0; i < 4; i++){
        const int row = i * 32 + (t >> 4);
        const int nf  = (t & 15) * 4;
        const f4v v = *(const f4v*)&FO[row * 68 + nf];
        const size_t idx = ((size_t)(b * CC + row)) * NN + q0 + nf;
        const f4v xv = *(const f4v*)&x[idx];
        f4v ov;
        #pragma unroll
        for (int r = 0; r < 4; r++) ov[r] = v[r] + xv[r];
        *(f4v*)&out[idx] = ov;
    }
}

// ---------------------------------------------------------------------------
// R25: single cooperative kernel -- pack -> grid.sync -> proj -> grid.sync ->
// attn. Removes 2 launch gaps, 2 dispatch tails, and pack_w's whole-GPU
// serialization. Grid 512x512 = 2 blocks/CU co-resident (LDS 48KB -> 3/CU
// capacity). __threadfence() = device-scope release across non-coherent XCD
// L2s (G16); grid.sync's acquire performs the matching invalidate.
// ---------------------------------------------------------------------------
__global__ __launch_bounds__(512, 4) void fused_kernel(
    const float* __restrict__ x,
    const float* __restrict__ wth, const float* __restrict__ wph,
    const float* __restrict__ wg,  const float* __restrict__ wl,
    float* __restrict__ out,
    f16* __restrict__ thetaT, f16* __restrict__ phiT, f16* __restrict__ gbuf,
    f16* __restrict__ wthp, f16* __restrict__ wphp,
    f16* __restrict__ wgp,  f16* __restrict__ wlp)
{
    __shared__ __align__(16) char SM[49152];
    const int bid = blockIdx.x, t = threadIdx.x;

    pack_body(bid * 512 + t, wth, wph, wg, wl, wthp, wphp, wgp, wlp);
    __threadfence();
    cg::this_grid().sync();

    proj_body(SM, bid, t, x, wthp, wphp, wgp, thetaT, phiT, gbuf);
    __threadfence();
    cg::this_grid().sync();

    attn_body(SM, bid, t, thetaT, phiT, gbuf, wlp, x, out);
}

// ---- fallback wrappers (used only if cooperative launch is unavailable) ----
__global__ __launch_bounds__(512) void pack_k(
    const float* __restrict__ wth, const float* __restrict__ wph,
    const float* __restrict__ wg,  const float* __restrict__ wl,
    f16* __restrict__ wthp, f16* __restrict__ wphp,
    f16* __restrict__ wgp,  f16* __restrict__ wlp)
{
    pack_body(blockIdx.x * 512 + threadIdx.x, wth, wph, wg, wl, wthp, wphp, wgp, wlp);
}

__global__ __launch_bounds__(512) void proj_k(
    const float* __restrict__ x, const f16* __restrict__ wthp,
    const f16* __restrict__ wphp, const f16* __restrict__ wgp,
    f16* __restrict__ thetaT, f16* __restrict__ phiT, f16* __restrict__ gbuf)
{
    __shared__ __align__(16) char SM[36864];
    proj_body(SM, blockIdx.x, threadIdx.x, x, wthp, wphp, wgp, thetaT, phiT, gbuf);
}

__global__ __launch_bounds__(512, 4) void attn_k(
    const f16* __restrict__ thetaT, const f16* __restrict__ phiT,
    const f16* __restrict__ gbuf, const f16* __restrict__ wlp,
    const float* __restrict__ x, float* __restrict__ out)
{
    __shared__ __align__(16) char SM[49152];
    attn_body(SM, blockIdx.x, threadIdx.x, thetaT, phiT, gbuf, wlp, x, out);
}

extern "C" void kernel_launch(void* const* d_in, const int* in_sizes, int n_in,
                              void* d_out, int out_size, void* d_ws, size_t ws_size,
                              hipStream_t stream)
{
    const float* x   = (const float*)d_in[0];
    const float* wth = (const float*)d_in[1];
    const float* wph = (const float*)d_in[2];
    const float* wg  = (const float*)d_in[3];
    const float* wl  = (const float*)d_in[4];
    float* out = (float*)d_out;

    f16* thetaT = (f16*)d_ws;
    f16* phiT   = thetaT + (size_t)NB * NN * CB;
    f16* gbuf   = phiT   + (size_t)NB * NN * CB;
    f16* wthp   = gbuf   + (size_t)NB * NN * CB;
    f16* wphp   = wthp + 8192;
    f16* wgp    = wphp + 8192;
    f16* wlp    = wgp  + 8192;

    void* args[] = {
        (void*)&x, (void*)&wth, (void*)&wph, (void*)&wg, (void*)&wl,
        (void*)&out, (void*)&thetaT, (void*)&phiT, (void*)&gbuf,
        (void*)&wthp, (void*)&wphp, (void*)&wgp, (void*)&wlp
    };
    hipError_t e = hipLaunchCooperativeKernel((const void*)fused_kernel,
                                              dim3(NB * 64), dim3(512),
                                              args, 0, stream);
    if (e != hipSuccess){
        // fallback: R24 three-kernel path
        pack_k<<<16, 512, 0, stream>>>(wth, wph, wg, wl, wthp, wphp, wgp, wlp);
        proj_k<<<NB * 64, 512, 0, stream>>>(x, wthp, wphp, wgp, thetaT, phiT, gbuf);
        attn_k<<<NB * 64, 512, 0, stream>>>(thetaT, phiT, gbuf, wlp, x, out);
    }
}

// Round 14
// 155.402 us; speedup vs baseline: 2.3911x; 2.3911x over previous
//
#include <hip/hip_runtime.h>
#include <stdint.h>

typedef _Float16 h8v __attribute__((ext_vector_type(8)));
typedef _Float16 h4v __attribute__((ext_vector_type(4)));
typedef float f4v __attribute__((ext_vector_type(4)));
typedef _Float16 f16;

#define NB 8
#define CC 128
#define CB 64
#define NN 4096
#define L2E 1.4426950408889634f

#define GLD(gp, lp) __builtin_amdgcn_global_load_lds( \
    (const __attribute__((address_space(1))) void*)(gp), \
    (__attribute__((address_space(3))) void*)(lp), 16, 0, 0)

#define WAITV2() asm volatile("s_waitcnt vmcnt(2)" ::: "memory")
#define WAITV0() asm volatile("s_waitcnt vmcnt(0)" ::: "memory")
#define WAITL0() asm volatile("s_waitcnt lgkmcnt(0)" ::: "memory")

// ---------------------------------------------------------------------------
// Kernel 1: projections. R24 wave-split structure + weight fragments DIRECT
// from f32 (R19-proven mapping) -- pack_w deleted.
//   waves 0-3: theta for n-group w&3;  waves 4-7: phi for n-group w&3
//   g: wave w -> cb-group w&3, ns-half w>>2
// ---------------------------------------------------------------------------
__global__ __launch_bounds__(512) void proj_kernel(
    const float* __restrict__ x, const float* __restrict__ wth,
    const float* __restrict__ wph, const float* __restrict__ wg,
    f16* __restrict__ thetaT, f16* __restrict__ phiT, f16* __restrict__ gbuf)
{
    __shared__ __align__(16) f16 xT[64][136];
    __shared__ __align__(16) f16 rep[8][16 * 72];
    const int b  = blockIdx.x & 7;
    const int n0 = (blockIdx.x >> 3) << 6;
    const int t  = threadIdx.x;

    #pragma unroll
    for (int i = 0; i < 4; i++){
        int v  = t + 512 * i;
        int c  = v >> 4;
        int j0 = (v & 15) << 2;
        const f4v xv = *(const f4v*)&x[((size_t)(b * CC + c)) * NN + n0 + j0];
        #pragma unroll
        for (int jj = 0; jj < 4; jj++) xT[j0 + jj][c] = (f16)xv[jj];
    }
    __syncthreads();

    const int w = t >> 6, lane = t & 63, quad = lane >> 4, l15 = lane & 15;
    const int wq = w & 3, grp = w >> 2;
    const int rrow = lane >> 3, rcol = (lane & 7) * 8;

    h8v bx[4];
    #pragma unroll
    for (int kc = 0; kc < 4; kc++)
        bx[kc] = *(const h8v*)&xT[wq * 16 + l15][kc * 32 + quad * 8];

    // ---- theta (grp==0) / phi (grp==1) for n-group wq; direct f32 weights ----
    {
        const float* WF = (grp == 0) ? wth : wph;
        const float sc = (grp == 0) ? L2E : 1.0f;   // theta pre-scaled for exp2
        f16* OUT       = (grp == 0) ? thetaT : phiT;
        for (int ks = 0; ks < 4; ks++){
            f4v acc = {0.f, 0.f, 0.f, 0.f};
            #pragma unroll
            for (int kc = 0; kc < 4; kc++){
                const float* wr = WF + (ks * 16 + l15) * CC + kc * 32 + quad * 8;
                const f4v wa = *(const f4v*)wr;
                const f4v wb = *(const f4v*)(wr + 4);
                h8v af;
                #pragma unroll
                for (int j = 0; j < 4; j++){
                    af[j]     = (f16)(wa[j] * sc);
                    af[4 + j] = (f16)(wb[j] * sc);
                }
                acc = __builtin_amdgcn_mfma_f32_16x16x32_f16(af, bx[kc], acc, 0, 0, 0);
            }
            h4v pv;
            #pragma unroll
            for (int r = 0; r < 4; r++) pv[r] = (f16)acc[r];
            *(h4v*)&rep[w][l15 * 72 + ks * 16 + quad * 4] = pv;
        }
        #pragma unroll
        for (int j = 0; j < 2; j++){
            const h8v vv = *(const h8v*)&rep[w][(rrow + 8 * j) * 72 + rcol];
            *(h8v*)&OUT[((size_t)(b * NN + n0 + wq * 16 + rrow + 8 * j)) * CB + rcol] = vv;
        }
    }
    __syncthreads();   // g below reuses rep[0..3]; theta reads must complete

    // ---- g: wave w -> cb-group wq, ns-half grp; direct f32 weights ----
    h8v bw[4];
    #pragma unroll
    for (int kc = 0; kc < 4; kc++){
        const float* wr = wg + (wq * 16 + l15) * CC + kc * 32 + quad * 8;
        const f4v wa = *(const f4v*)wr;
        const f4v wb = *(const f4v*)(wr + 4);
        #pragma unroll
        for (int j = 0; j < 4; j++){
            bw[kc][j]     = (f16)wa[j];
            bw[kc][4 + j] = (f16)wb[j];
        }
    }
    #pragma unroll
    for (int ns2 = 0; ns2 < 2; ns2++){
        const int ns = grp * 2 + ns2;
        f4v acc = {0.f, 0.f, 0.f, 0.f};
        #pragma unroll
        for (int kc = 0; kc < 4; kc++){
            const h8v af = *(const h8v*)&xT[ns * 16 + l15][kc * 32 + quad * 8];
            acc = __builtin_amdgcn_mfma_f32_16x16x32_f16(af, bw[kc], acc, 0, 0, 0);
        }
        h4v pv;
        #pragma unroll
        for (int r = 0; r < 4; r++) pv[r] = (f16)acc[r];
        *(h4v*)&rep[wq][l15 * 72 + ns * 16 + quad * 4] = pv;
    }
    __syncthreads();
    {
        const int row = rrow + 8 * grp;
        const h8v vv = *(const h8v*)&rep[wq][row * 72 + rcol];
        *(h8v*)&gbuf[((size_t)(b * CB + wq * 16 + row)) * NN + n0 + rcol] = vv;
    }
}

// ---------------------------------------------------------------------------
// Kernel 2: fused attention + final projection + residual.
// R26 = R23 core (P-in-register sigma PV, pre-permuted GG, counted vmcnt,
// raw barriers, compile-time slots, shuffle-free defer-max) reshaped to
// 128-KEY MACRO-STEPS (32 steps, half the barriers):
//   ph: 3 slots x 8192 f16 (48KB), gl_lds staged, vmcnt(2) rides ph(m+1)
//   GG: 2 slots x 8192 f16 (32KB), reg-staged sigma-store; slot written at
//       step m was last read at step m-1 (drained by lgkm(0)+barrier) - safe
//   per step: 4 staging ops {g-load x2, ph-GLD x2}; softmax fixed cost
//   (smax tree, defer branch, waitcnts, barrier) amortized over 64 keys/wave.
// LDS 80KB -> 2 blocks/CU (160/80), 4 waves/SIMD, unchanged occupancy.
// wl loaded direct f32 in epilogue (pack_w deleted).
// ---------------------------------------------------------------------------
__global__ __launch_bounds__(512, 4) void attn_kernel(
    const f16* __restrict__ thetaT, const f16* __restrict__ phiT,
    const f16* __restrict__ gbuf, const float* __restrict__ wl,
    const float* __restrict__ x, float* __restrict__ out)
{
    __shared__ __align__(16) char SM[81920];
    f16*   const PH  = (f16*)SM;                // [3][8192]   49152 B
    f16*   const GG  = (f16*)(SM + 49152);      // [2][8192]   32768 B
    // epilogue overlays (staging dead):
    float* const MG  = (float*)SM;              // [4][16][68] 17408 B
    float* const ML  = (float*)(SM + 17408);    // [4][16][2]    512 B
    float* const FO  = (float*)SM;              // [128][68]   34816 B
    f16*   const YY  = (f16*)(SM + 36864);      // [64][72]     9216 B

    const int b  = blockIdx.x & 7;              // batch -> XCD swizzle
    const int q0 = (blockIdx.x >> 3) << 6;
    const int t  = threadIdx.x;
    const int w  = t >> 6;                      // 0..7
    const int lane = t & 63, quad = lane >> 4, l15 = lane & 15;
    const int wq = w & 3;                       // query group
    const int h  = w >> 2;                      // key half within each 64-key pair
    const int n0 = q0 + wq * 16;

    // theta fragments (16 queries per wave)
    const size_t trow = ((size_t)(b * NN + n0 + l15)) * CB;
    const h8v a0 = *(const h8v*)&thetaT[trow + quad * 8];
    const h8v a1 = *(const h8v*)&thetaT[trow + 32 + quad * 8];

    // ---- staging (512 threads; srow = pair-local key/cb row 0..63) ----
    const int srow = t >> 3;
    const int skg  = t & 7;
    const f16* pS = phiT + ((size_t)(b * NN + srow)) * CB + (skg ^ (srow & 7)) * 8;
    const f16* pG = gbuf + ((size_t)(b * CB + srow)) * NN + skg * 8;
    // g sigma-store within a 4096-f16 pair block (R22-verified):
    const int sgs = (srow >> 1) & 3;
    const int cA  = (2 * (skg & 3)) & 3;
    const int gdA = (skg >> 2) * 2048 + srow * 32 + ((cA      ^ sgs) * 8) + ((skg >> 1) & 1) * 4;
    const int gdB = (skg >> 2) * 2048 + srow * 32 + (((cA | 1) ^ sgs) * 8) + ((skg >> 1) & 1) * 4;

    // read swizzles
    const int so0 = (quad ^ (l15 & 7)) * 8;           // ph b128 chunk
    const int so1 = so0 ^ 32;
    const int gvs = (quad ^ ((l15 >> 1) & 3)) * 8;    // GG sigma b128 chunk

    // base pointers; slot/pair/tt selects become compile-time offsets
    const f16* const PB0 = PH + h * 2048 + l15 * 64 + so0;
    const f16* const PB1 = PH + h * 2048 + l15 * 64 + so1;
    const f16* const GB  = GG + h * 2048 + l15 * 32 + gvs;
    f16* const WA = GG + gdA;
    f16* const WB = GG + gdB;
    f16* const PD = PH + t * 8;

    // ---- prologue: g steps 0,1 -> regs; ph steps 0,1 -> slots 0,1 ----
    h8v gA0 = *(const h8v*)pG;                  // g step 0, pair 0
    h8v gA1 = *(const h8v*)(pG + 64);           // g step 0, pair 1
    h8v gB0 = *(const h8v*)(pG + 128);          // g step 1, pair 0
    h8v gB1 = *(const h8v*)(pG + 192);          // g step 1, pair 1
    pG += 256;                                  // -> step 2
    GLD(pS,                     PD);
    GLD(pS + (size_t) 64 * CB,  PD + 4096);
    GLD(pS + (size_t)128 * CB,  PD + 8192);
    GLD(pS + (size_t)192 * CB,  PD + 12288);
    pS += (size_t)256 * CB;                     // -> step 2
    {   // write GG step 0 -> slot 0 (compiler waits for gA)
        h4v l0_, h0_, l1_, h1_;
        #pragma unroll
        for (int j = 0; j < 4; j++){
            l0_[j] = gA0[j]; h0_[j] = gA0[4 + j];
            l1_[j] = gA1[j]; h1_[j] = gA1[4 + j];
        }
        *(h4v*)&WA[0]    = l0_;  *(h4v*)&WB[0]    = h0_;
        *(h4v*)&WA[4096] = l1_;  *(h4v*)&WB[4096] = h1_;
    }

    float mrun = -1e30f, lrun = 0.f;
    const f4v zf = {0.f, 0.f, 0.f, 0.f};
    f4v o[4];
    #pragma unroll
    for (int tt = 0; tt < 4; tt++) o[tt] = zf;

// STEPK128(SL3, SL2R, SL2W, SLD, V2, DO_W, DO_L, gw0,gw1, gl0,gl1):
// step m: compute ph slot SL3=m%3, GG slot SL2R=m%2; write GG(m+1)->SL2W;
// load g(m+2)->gl; GLD ph(m+2)->slot SLD. Top-of-step vmcnt(2): g(m+1)
// landed (needed for DO_W), ph(m+1) GLDs ride across the barrier (T4).
#define STEPK128(SL3, SL2R, SL2W, SLD, V2, DO_W, DO_L, gw0, gw1, gl0, gl1) do { \
    if (V2) WAITV2(); else WAITV0();                                        \
    WAITL0();                                                               \
    __builtin_amdgcn_s_barrier();                                           \
    asm volatile("" ::: "memory");                                          \
    if (DO_W){                                                              \
        h4v l0_, h0_, l1_, h1_;                                             \
        _Pragma("unroll")                                                   \
        for (int j = 0; j < 4; j++){                                        \
            l0_[j] = gw0[j]; h0_[j] = gw0[4 + j];                           \
            l1_[j] = gw1[j]; h1_[j] = gw1[4 + j];                           \
        }                                                                   \
        *(h4v*)&WA[SL2W * 8192]        = l0_;                               \
        *(h4v*)&WB[SL2W * 8192]        = h0_;                               \
        *(h4v*)&WA[SL2W * 8192 + 4096] = l1_;                               \
        *(h4v*)&WB[SL2W * 8192 + 4096] = h1_;                               \
    }                                                                       \
    if (DO_L){                                                              \
        gl0 = *(const h8v*)pG;                                              \
        gl1 = *(const h8v*)(pG + 64);                                       \
        pG += 128;                                                          \
        __builtin_amdgcn_sched_barrier(0);                                  \
        GLD(pS,                   PD + SLD * 8192);                         \
        GLD(pS + (size_t)64 * CB, PD + SLD * 8192 + 4096);                  \
        pS += (size_t)128 * CB;                                             \
    }                                                                       \
    f4v s0_, s1_, s2_, s3_;                                                 \
    __builtin_amdgcn_s_setprio(1);                                          \
    {                                                                       \
        f4v sv = zf;                                                        \
        sv = __builtin_amdgcn_mfma_f32_16x16x32_f16(                        \
            *(const h8v*)(PB0 + SL3 * 8192), a0, sv, 0, 0, 0);              \
        sv = __builtin_amdgcn_mfma_f32_16x16x32_f16(                        \
            *(const h8v*)(PB1 + SL3 * 8192), a1, sv, 0, 0, 0);              \
        s0_ = sv;                                                           \
        f4v sw = zf;                                                        \
        sw = __builtin_amdgcn_mfma_f32_16x16x32_f16(                        \
            *(const h8v*)(PB0 + SL3 * 8192 + 1024), a0, sw, 0, 0, 0);       \
        sw = __builtin_amdgcn_mfma_f32_16x16x32_f16(                        \
            *(const h8v*)(PB1 + SL3 * 8192 + 1024), a1, sw, 0, 0, 0);       \
        s1_ = sw;                                                           \
        f4v sx = zf;                                                        \
        sx = __builtin_amdgcn_mfma_f32_16x16x32_f16(                        \
            *(const h8v*)(PB0 + SL3 * 8192 + 4096), a0, sx, 0, 0, 0);       \
        sx = __builtin_amdgcn_mfma_f32_16x16x32_f16(                        \
            *(const h8v*)(PB1 + SL3 * 8192 + 4096), a1, sx, 0, 0, 0);       \
        s2_ = sx;                                                           \
        f4v sy = zf;                                                        \
        sy = __builtin_amdgcn_mfma_f32_16x16x32_f16(                        \
            *(const h8v*)(PB0 + SL3 * 8192 + 5120), a0, sy, 0, 0, 0);       \
        sy = __builtin_amdgcn_mfma_f32_16x16x32_f16(                        \
            *(const h8v*)(PB1 + SL3 * 8192 + 5120), a1, sy, 0, 0, 0);       \
        s3_ = sy;                                                           \
    }                                                                       \
    __builtin_amdgcn_s_setprio(0);                                          \
    float smax_ = fmaxf(fmaxf(s0_[0], s0_[1]), fmaxf(s0_[2], s0_[3]));      \
    smax_ = fmaxf(smax_, fmaxf(fmaxf(s1_[0], s1_[1]), fmaxf(s1_[2], s1_[3])));\
    smax_ = fmaxf(smax_, fmaxf(fmaxf(s2_[0], s2_[1]), fmaxf(s2_[2], s2_[3])));\
    smax_ = fmaxf(smax_, fmaxf(fmaxf(s3_[0], s3_[1]), fmaxf(s3_[2], s3_[3])));\
    if (__any(smax_ - mrun > 8.f)){                                         \
        smax_ = fmaxf(smax_, __shfl_xor(smax_, 16));                        \
        smax_ = fmaxf(smax_, __shfl_xor(smax_, 32));                        \
        const float mn_ = fmaxf(mrun, smax_);                               \
        const float al_ = __builtin_amdgcn_exp2f(mrun - mn_);               \
        mrun = mn_;                                                         \
        lrun *= al_;                                                        \
        _Pragma("unroll")                                                   \
        for (int tt = 0; tt < 4; tt++)                                      \
            _Pragma("unroll")                                               \
            for (int r = 0; r < 4; r++)                                     \
                o[tt][r] *= al_;                                            \
    }                                                                       \
    float lsum_ = 0.f;                                                      \
    h8v pa0_, pa1_;                                                         \
    _Pragma("unroll")                                                       \
    for (int r = 0; r < 4; r++){                                            \
        float p_ = __builtin_amdgcn_exp2f(s0_[r] - mrun);                   \
        lsum_ += p_;  pa0_[r] = (f16)p_;                                    \
        float q_ = __builtin_amdgcn_exp2f(s1_[r] - mrun);                   \
        lsum_ += q_;  pa0_[4 + r] = (f16)q_;                                \
        float u_ = __builtin_amdgcn_exp2f(s2_[r] - mrun);                   \
        lsum_ += u_;  pa1_[r] = (f16)u_;                                    \
        float v_ = __builtin_amdgcn_exp2f(s3_[r] - mrun);                   \
        lsum_ += v_;  pa1_[4 + r] = (f16)v_;                                \
    }                                                                       \
    lrun += lsum_;                                                          \
    __builtin_amdgcn_s_setprio(1);                                          \
    o[0] = __builtin_amdgcn_mfma_f32_16x16x32_f16(                          \
        *(const h8v*)(GB + SL2R * 8192 +    0), pa0_, o[0], 0, 0, 0);       \
    o[1] = __builtin_amdgcn_mfma_f32_16x16x32_f16(                          \
        *(const h8v*)(GB + SL2R * 8192 +  512), pa0_, o[1], 0, 0, 0);       \
    o[2] = __builtin_amdgcn_mfma_f32_16x16x32_f16(                          \
        *(const h8v*)(GB + SL2R * 8192 + 1024), pa0_, o[2], 0, 0, 0);       \
    o[3] = __builtin_amdgcn_mfma_f32_16x16x32_f16(                          \
        *(const h8v*)(GB + SL2R * 8192 + 1536), pa0_, o[3], 0, 0, 0);       \
    o[0] = __builtin_amdgcn_mfma_f32_16x16x32_f16(                          \
        *(const h8v*)(GB + SL2R * 8192 + 4096), pa1_, o[0], 0, 0, 0);       \
    o[1] = __builtin_amdgcn_mfma_f32_16x16x32_f16(                          \
        *(const h8v*)(GB + SL2R * 8192 + 4608), pa1_, o[1], 0, 0, 0);       \
    o[2] = __builtin_amdgcn_mfma_f32_16x16x32_f16(                          \
        *(const h8v*)(GB + SL2R * 8192 + 5120), pa1_, o[2], 0, 0, 0);       \
    o[3] = __builtin_amdgcn_mfma_f32_16x16x32_f16(                          \
        *(const h8v*)(GB + SL2R * 8192 + 5632), pa1_, o[3], 0, 0, 0);       \
    __builtin_amdgcn_s_setprio(0);                                          \
} while (0)

    // m = 0..29: 5 x 6-unrolled (lcm of ph slot %3, GG slot %2, g ping-pong)
    for (int mm = 0; mm < 30; mm += 6){
        STEPK128(0, 0, 1, 2, 1, 1, 1, gB0, gB1, gA0, gA1);
        STEPK128(1, 1, 0, 0, 1, 1, 1, gA0, gA1, gB0, gB1);
        STEPK128(2, 0, 1, 1, 1, 1, 1, gB0, gB1, gA0, gA1);
        STEPK128(0, 1, 0, 2, 1, 1, 1, gA0, gA1, gB0, gB1);
        STEPK128(1, 0, 1, 0, 1, 1, 1, gB0, gB1, gA0, gA1);
        STEPK128(2, 1, 0, 1, 1, 1, 1, gA0, gA1, gB0, gB1);
    }
    STEPK128(0, 0, 1, 2, 1, 1, 0, gB0, gB1, gA0, gA1);   // m=30: write GG(31)
    STEPK128(1, 1, 0, 0, 0, 0, 0, gA0, gA1, gB0, gB1);   // m=31: drain, compute
#undef STEPK128

    // per-wave l reduce across quads (full l for this wave's key half)
    lrun += __shfl_xor(lrun, 16);
    lrun += __shfl_xor(lrun, 32);

    __syncthreads();   // K-loop done; staging region dead -> merge overlay

    if (h == 1){       // odd-half waves publish (m, l, O)
        #pragma unroll
        for (int tt2 = 0; tt2 < 4; tt2++)
            *(f4v*)&MG[wq * 1088 + l15 * 68 + tt2 * 16 + quad * 4] = o[tt2];
        if (lane < 16){
            ML[wq * 32 + lane * 2 + 0] = mrun;
            ML[wq * 32 + lane * 2 + 1] = lrun;
        }
    }
    __syncthreads();

    if (h == 0){       // even-half waves merge + normalize -> y (f16)
        const float m4 = ML[wq * 32 + l15 * 2 + 0];
        const float l4 = ML[wq * 32 + l15 * 2 + 1];
        const float M  = fmaxf(mrun, m4);
        const float e0 = __builtin_amdgcn_exp2f(mrun - M);
        const float e1 = __builtin_amdgcn_exp2f(m4 - M);
        const float inv = 1.0f / (lrun * e0 + l4 * e1);
        #pragma unroll
        for (int tt2 = 0; tt2 < 4; tt2++){
            const f4v o4 = *(const f4v*)&MG[wq * 1088 + l15 * 68 + tt2 * 16 + quad * 4];
            h4v yv;
            #pragma unroll
            for (int r = 0; r < 4; r++)
                yv[r] = (f16)((o[tt2][r] * e0 + o4[r] * e1) * inv);
            *(h4v*)&YY[(wq * 16 + l15) * 72 + tt2 * 16 + quad * 4] = yv;
        }
    }
    __syncthreads();

    // ---- out-GEMM: D[c][q] = wl(A) * y(B); wl fragments direct f32 ----
    const f4v zf2 = {0.f, 0.f, 0.f, 0.f};
    const h8v yB0 = *(const h8v*)&YY[(wq * 16 + l15) * 72 + quad * 8];
    const h8v yB1 = *(const h8v*)&YY[(wq * 16 + l15) * 72 + 32 + quad * 8];
    #pragma unroll
    for (int ci = 0; ci < 4; ci++){
        const int cs = h * 4 + ci;
        const float* wrow = wl + (cs * 16 + l15) * CB + quad * 8;
        const f4v wA0 = *(const f4v*)(wrow);
        const f4v wA1 = *(const f4v*)(wrow + 4);
        const f4v wB0 = *(const f4v*)(wrow + 32);
        const f4v wB1 = *(const f4v*)(wrow + 36);
        h8v wa0, wa1;
        #pragma unroll
        for (int j = 0; j < 4; j++){
            wa0[j]     = (f16)wA0[j];
            wa0[4 + j] = (f16)wA1[j];
            wa1[j]     = (f16)wB0[j];
            wa1[4 + j] = (f16)wB1[j];
        }
        f4v acc = zf2;
        acc = __builtin_amdgcn_mfma_f32_16x16x32_f16(wa0, yB0, acc, 0, 0, 0);
        acc = __builtin_amdgcn_mfma_f32_16x16x32_f16(wa1, yB1, acc, 0, 0, 0);
        #pragma unroll
        for (int r = 0; r < 4; r++)
            FO[(cs * 16 + quad * 4 + r) * 68 + wq * 16 + l15] = acc[r];
    }
    __syncthreads();

    // ---- residual RMW: fully coalesced float4, 512 threads ----
    #pragma unroll
    for (int i = 0; i < 4; i++){
        const int row = i * 32 + (t >> 4);
        const int nf  = (t & 15) * 4;
        const f4v v = *(const f4v*)&FO[row * 68 + nf];
        const size_t idx = ((size_t)(b * CC + row)) * NN + q0 + nf;
        const f4v xv = *(const f4v*)&x[idx];
        f4v ov;
        #pragma unroll
        for (int r = 0; r < 4; r++) ov[r] = v[r] + xv[r];
        *(f4v*)&out[idx] = ov;
    }
}

extern "C" void kernel_launch(void* const* d_in, const int* in_sizes, int n_in,
                              void* d_out, int out_size, void* d_ws, size_t ws_size,
                              hipStream_t stream)
{
    const float* x   = (const float*)d_in[0];
    const float* wth = (const float*)d_in[1];
    const float* wph = (const float*)d_in[2];
    const float* wg  = (const float*)d_in[3];
    const float* wl  = (const float*)d_in[4];
    float* out = (float*)d_out;

    f16* thetaT = (f16*)d_ws;
    f16* phiT   = thetaT + (size_t)NB * NN * CB;
    f16* gbuf   = phiT   + (size_t)NB * NN * CB;

    proj_kernel<<<NB * 64, 512, 0, stream>>>(x, wth, wph, wg, thetaT, phiT, gbuf);
    attn_kernel<<<NB * 64, 512, 0, stream>>>(thetaT, phiT, gbuf, wl, x, out);
}